// Round 4
// baseline (107.897 us; speedup 1.0000x reference)
//
#include <hip/hip_runtime.h>

// ---------------------------------------------------------------------------
// DynamicEncoder via MFMA (gfx950, mfma_f32_16x16x32_bf16).
//
// Round 4: A-fragments prefetched to VGPRs + fully unrolled k-loops (kills
// per-iteration global-load stalls); stage1 LDS stride 232->256 with XOR
// swizzle on write+read (kills ~4-way bank conflicts); swizzled epilogue.
//
// Stage1: x (64, 2047(+1 zero), 100ch) -> y0 bf16 [b][1024 t][112 ch]
//   7 pool-PAIRS, union <= 8 nodes x 4 ci = 32 cin = one K-step, 15 taps.
// Stage2: y0 -> out fp32 (64, 112, 512); 7 pools, union <= 64 cin = 2 K-steps.
//
// Workspace (bytes):
//   A1  @ 0      : [7 g][15 k][64 lane][8] bf16 = 107520
//   A2  @ 107520 : [7 p][2 ks][15 k][64][8] bf16 = 215040
//   BF0 @ 322560 : 112 f32 ; BF1 @ 323008 : 112 f32
//   Y0  @ 323584 : [64 b][1024 t][112 ch] bf16 = 14680064
// ---------------------------------------------------------------------------

#define OFF_A2  107520u
#define OFF_BF0 322560u
#define OFF_BF1 323008u
#define OFF_Y0  323584u

typedef unsigned int uint32;
typedef __attribute__((ext_vector_type(8))) short bs8;
typedef __attribute__((ext_vector_type(4))) float f32x4;
union U8 { uint4 u; bs8 s; };

// ---- graph constants (verified rounds 1-3) ----
__constant__ int c_pool0_len[14] = {2,2,2,2,1,2,2,1,2,2,1,2,2,2};
__constant__ int c_pool0_mem[14][2] = {{0,3},{6,9},{1,4},{7,10},{2,2},{5,8},{11,14},{12,12},
                                       {15,17},{19,21},{13,13},{16,18},{20,22},{23,24}};
__constant__ unsigned c_nbm0[25] = {
 0x180000Fu,0x1800017u,0x1800027u,0x1800049u,0x92u,0x124u,0x248u,0x490u,
 0x3920u,0x240u,0x480u,0x7900u,0xB900u,0x13900u,0x4800u,0x29000u,
 0x52000u,0xA8000u,0x150000u,0x2A0000u,0x540000u,0x280000u,0x500000u,
 0x180000Fu,0x180000Fu
};
__constant__ int c_pool1_len[7] = {2,2,2,1,3,3,1};
__constant__ int c_pool1_mem[7][3] = {{0,1,1},{2,3,3},{4,5,5},{6,6,6},{7,8,9},{10,11,12},{13,13,13}};
__constant__ unsigned c_nbm1[14] = {
 0x2017u,0x2003u,0x201Du,0xCu,0x2035u,0x4F0u,0x4E0u,0x5E0u,
 0x380u,0x300u,0xCE0u,0x1C00u,0x1800u,0x2017u
};
// stage1 pool pairs and their combined unions (pad node 25 = zero channels)
__constant__ int c_g1p[7][2] = {{0,13},{1,3},{2,4},{5,6},{7,10},{8,11},{9,12}};
__constant__ int c_U1[7][8] = {
 {0,1,2,3,6,23,24,25},
 {3,4,6,7,9,10,25,25},
 {0,1,2,4,5,7,23,24},
 {2,5,8,11,12,13,14,25},
 {8,11,12,13,15,16,25,25},
 {12,13,15,16,17,18,19,20},
 {17,18,19,20,21,22,25,25}};
// stage2 unions (pad node 14 = zero channels)
__constant__ int c_U2[7][8] = {
 {0,1,2,4,13,14,14,14},
 {0,2,3,4,13,14,14,14},
 {0,2,4,5,6,7,10,13},
 {5,6,7,10,14,14,14,14},
 {5,6,7,8,9,10,14,14},
 {5,6,7,10,11,12,14,14},
 {0,1,2,4,13,14,14,14}};
// packed per-lane-group LDS byte offsets (node*8 stage1, node*16 stage2)
__constant__ unsigned c_pk1a[7] = {0xC0301000u,0xC8483018u,0xB8281000u,0x70604010u,
                                   0xC8786040u,0x98887860u,0xC8A89888u};
__constant__ unsigned c_pk1b[7] = {0xC8B81808u,0xC8503820u,0xC0382008u,0xC8685828u,
                                   0xC8806858u,0xA0908068u,0xC8B0A090u};
__constant__ unsigned c_pk2[7][2] = {
 {0x40201000u,0xE0E0E0D0u},{0x40302000u,0xE0E0E0D0u},{0x50402000u,0xD0A07060u},
 {0xA0706050u,0xE0E0E0E0u},{0x80706050u,0xE0E0A090u},{0xA0706050u,0xE0E0C0B0u},
 {0x40201000u,0xE0E0E0D0u}};

__device__ __forceinline__ uint32 f2bf(float v) {
  uint32 u = __float_as_uint(v);
  return (u + 0x7fffu + ((u >> 16) & 1u)) >> 16;   // RNE
}

// ---------------------------------------------------------------------------
// Prep: bake fused (mask x pool-mean) weights straight into A-fragment order.
// ---------------------------------------------------------------------------
__global__ void prep_fused_weights(const float* __restrict__ w0, const float* __restrict__ b0,
                                   const float* __restrict__ w1, const float* __restrict__ b1,
                                   char* __restrict__ wsb) {
  int t = blockIdx.x * blockDim.x + threadIdx.x;
  if (t < 6720) {                       // A1: [7 g][15 k][64 lane] uint4
    int lane = t & 63;
    int r = t >> 6;
    int k = r % 15, g = r / 15;
    int m = lane & 15, h = lane >> 4;
    int pool = (m < 8) ? c_g1p[g][0] : c_g1p[g][1];
    int c = m & 7;
    int L = c_pool0_len[pool];
    float inv = 1.f / (float)L;
    uint32 us[8];
#pragma unroll
    for (int j = 0; j < 8; ++j) {
      int node = c_U1[g][2 * h + (j >> 2)];
      int ci = j & 3;
      float v = 0.f;
      if (node < 25) {
        for (int jj = 0; jj < L; ++jj) {
          int mem = c_pool0_mem[pool][jj];
          if ((c_nbm0[mem] >> node) & 1u)
            v += w0[(mem * 8 + c) * 1500 + (node * 4 + ci) * 15 + k];
        }
        v *= inv;
      }
      us[j] = f2bf(v);
    }
    uint4 o = make_uint4(us[0] | (us[1] << 16), us[2] | (us[3] << 16),
                         us[4] | (us[5] << 16), us[6] | (us[7] << 16));
    reinterpret_cast<uint4*>(wsb)[t] = o;
  } else if (t < 6720 + 13440) {        // A2: [7 p][2 ks][15 k][64 lane] uint4
    int t2 = t - 6720;
    int lane = t2 & 63;
    int r = t2 >> 6;
    int k = r % 15;
    int r2 = r / 15;
    int ks = r2 & 1, p = r2 >> 1;
    int c = lane & 15, h = lane >> 4;
    int node = c_U2[p][ks * 4 + h];
    int L = c_pool1_len[p];
    float inv = 1.f / (float)L;
    uint32 us[8];
#pragma unroll
    for (int j = 0; j < 8; ++j) {
      float v = 0.f;
      if (node < 14) {
        for (int jj = 0; jj < L; ++jj) {
          int mem = c_pool1_mem[p][jj];
          if ((c_nbm1[mem] >> node) & 1u)
            v += w1[(mem * 16 + c) * 1680 + (node * 8 + j) * 15 + k];
        }
        v *= inv;
      }
      us[j] = f2bf(v);
    }
    uint4 o = make_uint4(us[0] | (us[1] << 16), us[2] | (us[3] << 16),
                         us[4] | (us[5] << 16), us[6] | (us[7] << 16));
    reinterpret_cast<uint4*>(wsb + OFF_A2)[t2] = o;
  } else if (t < 6720 + 13440 + 112) {  // BF0
    int p = t - (6720 + 13440);
    int i = p >> 3, c = p & 7;
    int L = c_pool0_len[i];
    float v = 0.f;
    for (int jj = 0; jj < L; ++jj) v += b0[c_pool0_mem[i][jj] * 8 + c];
    reinterpret_cast<float*>(wsb + OFF_BF0)[p] = v / (float)L;
  } else if (t < 6720 + 13440 + 224) {  // BF1
    int p = t - (6720 + 13440 + 112);
    int i = p >> 4, c = p & 15;
    int L = c_pool1_len[i];
    float v = 0.f;
    for (int jj = 0; jj < L; ++jj) v += b1[c_pool1_mem[i][jj] * 16 + c];
    reinterpret_cast<float*>(wsb + OFF_BF1)[p] = v / (float)L;
  }
}

// ---------------------------------------------------------------------------
// Stage 1: 448 thr = 7 waves (wave = pool pair). t-tile 64.
// LDS [141 frames][256 B] bf16, XOR-swizzled 8B units. A prefetched, k-loop
// fully unrolled. Output transposed in LDS -> y0 [b][t][112] bf16.
// ---------------------------------------------------------------------------
__global__ __launch_bounds__(448, 7) void conv_stage1(const float* __restrict__ x,
                                                      const char* __restrict__ wsb,
                                                      char* __restrict__ y0b) {
  __shared__ __align__(16) unsigned char xs[141 * 256];  // 36.1 KB
  const int tid = threadIdx.x;
  const int lane = tid & 63;
  const int g = tid >> 6;            // wave = pair index 0..6
  const int m16 = lane & 15, h = lane >> 4;
  const int b = blockIdx.y;
  const int t0 = blockIdx.x << 6;
  const int g0 = 2 * t0 - 7;

  // prefetch A fragments + bias (L2 resident) before staging
  const uint4* __restrict__ A1p = reinterpret_cast<const uint4*>(wsb) + g * 960 + lane;
  U8 a[15];
#pragma unroll
  for (int k = 0; k < 15; ++k) a[k].u = A1p[k * 64];
  const int pa = c_g1p[g][0], pb = c_g1p[g][1];
  const int chbase = (h < 2) ? (pa * 8 + 4 * h) : (pb * 8 + 4 * (h - 2));
  const float4 bv = *reinterpret_cast<const float4*>(wsb + OFF_BF0 + chbase * 4);

  // stage: frame-major, fp32 -> bf16, swizzled 8B units (q<25 data, 25-28 pad)
  const float* __restrict__ xb = x + (size_t)b * (2047 * 100);
  for (int e = tid; e < 141 * 32; e += 448) {
    int f = e >> 5, q = e & 31;
    if (q >= 29) continue;
    uint2 w = make_uint2(0u, 0u);
    int gt = g0 + f;
    if (q < 25 && (unsigned)gt < 2047u) {
      float4 v = *reinterpret_cast<const float4*>(xb + gt * 100 + 4 * q);
      w.x = f2bf(v.x) | (f2bf(v.y) << 16);
      w.y = f2bf(v.z) | (f2bf(v.w) << 16);
    }
    *reinterpret_cast<uint2*>(xs + f * 256 + ((q * 8) ^ (((f >> 1) & 7) << 3))) = w;
  }
  __syncthreads();

  const uint32 offA = (c_pk1a[g] >> (8 * h)) & 255u;
  const uint32 offB = (c_pk1b[g] >> (8 * h)) & 255u;

  f32x4 acc[4];
#pragma unroll
  for (int nt = 0; nt < 4; ++nt) acc[nt] = (f32x4)0.f;

#pragma unroll
  for (int k = 0; k < 15; ++k) {
    // frame = 2*(nt*16+m16)+k; swizzle = ((frame>>1)&7)<<3 = ((m16+(k>>1))&7)<<3
    const uint32 sw = (uint32)(((m16 + (k >> 1)) & 7) << 3);
    const uint32 a0 = offA ^ sw, a1 = offB ^ sw;
    const unsigned char* base = xs + (2 * m16 + k) * 256;
#pragma unroll
    for (int nt = 0; nt < 4; ++nt) {
      uint2 lo = *reinterpret_cast<const uint2*>(base + nt * 8192 + a0);
      uint2 hi = *reinterpret_cast<const uint2*>(base + nt * 8192 + a1);
      U8 bfr; bfr.u = make_uint4(lo.x, lo.y, hi.x, hi.y);
      acc[nt] = __builtin_amdgcn_mfma_f32_16x16x32_bf16(a[k].s, bfr.s, acc[nt], 0, 0, 0);
    }
  }

  // epilogue: bias+relu, pack bf16, swizzled transpose via LDS, coalesced store
  __syncthreads();   // all LDS reads done before overwrite
#pragma unroll
  for (int nt = 0; nt < 4; ++nt) {
    float o0 = fmaxf(acc[nt][0] + bv.x, 0.f);
    float o1 = fmaxf(acc[nt][1] + bv.y, 0.f);
    float o2 = fmaxf(acc[nt][2] + bv.z, 0.f);
    float o3 = fmaxf(acc[nt][3] + bv.w, 0.f);
    uint2 wpk = make_uint2(f2bf(o0) | (f2bf(o1) << 16), f2bf(o2) | (f2bf(o3) << 16));
    int row = nt * 16 + m16;
    *reinterpret_cast<uint2*>(xs + row * 256 + ((chbase * 2) ^ ((row & 7) << 3))) = wpk;
  }
  __syncthreads();
  for (int e = tid; e < 1024; e += 448) {
    int row = e >> 4, q = e & 15;
    if (q >= 14) continue;
    uint32 sw = (uint32)((row & 7) << 3);
    uint2 av = *reinterpret_cast<const uint2*>(xs + row * 256 + ((q * 16) ^ sw));
    uint2 dv = *reinterpret_cast<const uint2*>(xs + row * 256 + ((q * 16 + 8) ^ sw));
    *reinterpret_cast<uint4*>(y0b + (size_t)(b * 1024 + t0 + row) * 224 + q * 16) =
        make_uint4(av.x, av.y, dv.x, dv.y);
  }
}

// ---------------------------------------------------------------------------
// Stage 2: 448 thr = 7 waves (wave = pool). t-tile 32, LDS [80 rows][256 B]
// bf16 (parity-split rows, 16B XOR swizzle). A prefetched, fully unrolled.
// ---------------------------------------------------------------------------
__global__ __launch_bounds__(448, 7) void conv_stage2(const char* __restrict__ wsb,
                                                      const char* __restrict__ y0b,
                                                      float* __restrict__ out) {
  __shared__ __align__(16) unsigned char xs[80 * 256];  // 20.5 KB
  const int tid = threadIdx.x;
  const int lane = tid & 63;
  const int p = tid >> 6;           // wave = pool 0..6
  const int m16 = lane & 15, h = lane >> 4;
  const int b = blockIdx.y;
  const int t0 = blockIdx.x << 5;
  const int g0 = 2 * t0 - 7;

  // prefetch all 30 A fragments + bias
  const uint4* __restrict__ A2p = reinterpret_cast<const uint4*>(wsb + OFF_A2) + p * 1920 + lane;
  U8 a[30];
#pragma unroll
  for (int kk = 0; kk < 30; ++kk) a[kk].u = A2p[kk * 64];
  const float4 bv = *reinterpret_cast<const float4*>(wsb + OFF_BF1 + (p * 16 + 4 * h) * 4);

  // stage: row copy y0[t][112] -> LDS [pr][256B] (q=14,15 zero pad nodes)
  const char* __restrict__ yb = y0b + (size_t)b * (1024 * 224);
  for (int e = tid; e < 77 * 16; e += 448) {
    int f = e >> 4, q = e & 15;
    uint4 v = make_uint4(0u, 0u, 0u, 0u);
    int gt = g0 + f;
    if (q < 14 && (unsigned)gt < 1024u)
      v = *reinterpret_cast<const uint4*>(yb + (size_t)gt * 224 + q * 16);
    int pr = (f >> 1) + (f & 1) * 40;
    *reinterpret_cast<uint4*>(xs + pr * 256 + ((q * 16) ^ ((pr & 7) << 4))) = v;
  }
  __syncthreads();

  f32x4 acc[2];
  acc[0] = (f32x4)0.f; acc[1] = (f32x4)0.f;
  const uint32 mbase = (uint32)(m16 * 256);

#pragma unroll
  for (int ks = 0; ks < 2; ++ks) {
    const uint32 noff = (c_pk2[p][ks] >> (8 * h)) & 255u;
#pragma unroll
    for (int k = 0; k < 15; ++k) {
      // pr = nt*16 + m16 + prk; pr&7 = (m16+(k>>1))&7 (prk = (k>>1)+(k&1)*40)
      const uint32 sw = (uint32)(((m16 + (k >> 1)) & 7) << 4);
      const uint32 ab = mbase + (noff ^ sw);
      const int imm = ((k >> 1) + (k & 1) * 40) * 256;
      U8 b0f, b1f;
      b0f.u = *reinterpret_cast<const uint4*>(xs + ab + imm);
      b1f.u = *reinterpret_cast<const uint4*>(xs + ab + imm + 4096);
      acc[0] = __builtin_amdgcn_mfma_f32_16x16x32_bf16(a[ks * 15 + k].s, b0f.s, acc[0], 0, 0, 0);
      acc[1] = __builtin_amdgcn_mfma_f32_16x16x32_bf16(a[ks * 15 + k].s, b1f.s, acc[1], 0, 0, 0);
    }
  }

#pragma unroll
  for (int nt = 0; nt < 2; ++nt) {
    size_t obase = ((size_t)b * 112 + p * 16 + 4 * h) * 512 + t0 + nt * 16 + m16;
    out[obase]        = fmaxf(acc[nt][0] + bv.x, 0.f);
    out[obase + 512]  = fmaxf(acc[nt][1] + bv.y, 0.f);
    out[obase + 1024] = fmaxf(acc[nt][2] + bv.z, 0.f);
    out[obase + 1536] = fmaxf(acc[nt][3] + bv.w, 0.f);
  }
}

extern "C" void kernel_launch(void* const* d_in, const int* in_sizes, int n_in,
                              void* d_out, int out_size, void* d_ws, size_t ws_size,
                              hipStream_t stream) {
  const float* x  = (const float*)d_in[0];
  const float* w0 = (const float*)d_in[1];
  const float* b0 = (const float*)d_in[2];
  const float* w1 = (const float*)d_in[3];
  const float* b1 = (const float*)d_in[4];
  char* wsb = (char*)d_ws;
  float* out = (float*)d_out;

  prep_fused_weights<<<80, 256, 0, stream>>>(w0, b0, w1, b1, wsb);
  conv_stage1<<<dim3(16, 64), 448, 0, stream>>>(x, wsb, wsb + OFF_Y0);
  conv_stage2<<<dim3(16, 64), 448, 0, stream>>>(wsb, wsb + OFF_Y0, out);
}

// Round 5
// 61.776 us; speedup vs baseline: 1.7466x; 1.7466x over previous
//
#include <hip/hip_runtime.h>

// ---------------------------------------------------------------------------
// DynamicEncoder via MFMA (gfx950, mfma_f32_16x16x32_bf16).
//
// Round 5: fix round-4 catastrophic spill — __launch_bounds__(448,7) capped
// VGPR at 73 while prefetch needed ~110/~160 (VGPR_Count=36 + 110MB scratch
// traffic in counters). Now (448,4) => 128 VGPR cap, 2 blocks/CU; stage2's
// A-prefetch split into two 15-fragment halves to fit.
//
// Stage1: x (64, 2047(+1 zero), 100ch) -> y0 bf16 [b][1024 t][112 ch]
//   7 pool-PAIRS, union <= 8 nodes x 4 ci = 32 cin = one K-step, 15 taps.
// Stage2: y0 -> out fp32 (64, 112, 512); 7 pools, union <= 64 cin = 2 K-steps.
//
// Workspace (bytes):
//   A1  @ 0      : [7 g][15 k][64 lane][8] bf16 = 107520
//   A2  @ 107520 : [7 p][2 ks][15 k][64][8] bf16 = 215040
//   BF0 @ 322560 : 112 f32 ; BF1 @ 323008 : 112 f32
//   Y0  @ 323584 : [64 b][1024 t][112 ch] bf16 = 14680064
// ---------------------------------------------------------------------------

#define OFF_A2  107520u
#define OFF_BF0 322560u
#define OFF_BF1 323008u
#define OFF_Y0  323584u

typedef unsigned int uint32;
typedef __attribute__((ext_vector_type(8))) short bs8;
typedef __attribute__((ext_vector_type(4))) float f32x4;
union U8 { uint4 u; bs8 s; };

// ---- graph constants (verified rounds 1-3) ----
__constant__ int c_pool0_len[14] = {2,2,2,2,1,2,2,1,2,2,1,2,2,2};
__constant__ int c_pool0_mem[14][2] = {{0,3},{6,9},{1,4},{7,10},{2,2},{5,8},{11,14},{12,12},
                                       {15,17},{19,21},{13,13},{16,18},{20,22},{23,24}};
__constant__ unsigned c_nbm0[25] = {
 0x180000Fu,0x1800017u,0x1800027u,0x1800049u,0x92u,0x124u,0x248u,0x490u,
 0x3920u,0x240u,0x480u,0x7900u,0xB900u,0x13900u,0x4800u,0x29000u,
 0x52000u,0xA8000u,0x150000u,0x2A0000u,0x540000u,0x280000u,0x500000u,
 0x180000Fu,0x180000Fu
};
__constant__ int c_pool1_len[7] = {2,2,2,1,3,3,1};
__constant__ int c_pool1_mem[7][3] = {{0,1,1},{2,3,3},{4,5,5},{6,6,6},{7,8,9},{10,11,12},{13,13,13}};
__constant__ unsigned c_nbm1[14] = {
 0x2017u,0x2003u,0x201Du,0xCu,0x2035u,0x4F0u,0x4E0u,0x5E0u,
 0x380u,0x300u,0xCE0u,0x1C00u,0x1800u,0x2017u
};
// stage1 pool pairs and their combined unions (pad node 25 = zero channels)
__constant__ int c_g1p[7][2] = {{0,13},{1,3},{2,4},{5,6},{7,10},{8,11},{9,12}};
__constant__ int c_U1[7][8] = {
 {0,1,2,3,6,23,24,25},
 {3,4,6,7,9,10,25,25},
 {0,1,2,4,5,7,23,24},
 {2,5,8,11,12,13,14,25},
 {8,11,12,13,15,16,25,25},
 {12,13,15,16,17,18,19,20},
 {17,18,19,20,21,22,25,25}};
// stage2 unions (pad node 14 = zero channels)
__constant__ int c_U2[7][8] = {
 {0,1,2,4,13,14,14,14},
 {0,2,3,4,13,14,14,14},
 {0,2,4,5,6,7,10,13},
 {5,6,7,10,14,14,14,14},
 {5,6,7,8,9,10,14,14},
 {5,6,7,10,11,12,14,14},
 {0,1,2,4,13,14,14,14}};
// packed per-lane-group LDS byte offsets (node*8 stage1, node*16 stage2)
__constant__ unsigned c_pk1a[7] = {0xC0301000u,0xC8483018u,0xB8281000u,0x70604010u,
                                   0xC8786040u,0x98887860u,0xC8A89888u};
__constant__ unsigned c_pk1b[7] = {0xC8B81808u,0xC8503820u,0xC0382008u,0xC8685828u,
                                   0xC8806858u,0xA0908068u,0xC8B0A090u};
__constant__ unsigned c_pk2[7][2] = {
 {0x40201000u,0xE0E0E0D0u},{0x40302000u,0xE0E0E0D0u},{0x50402000u,0xD0A07060u},
 {0xA0706050u,0xE0E0E0E0u},{0x80706050u,0xE0E0A090u},{0xA0706050u,0xE0E0C0B0u},
 {0x40201000u,0xE0E0E0D0u}};

__device__ __forceinline__ uint32 f2bf(float v) {
  uint32 u = __float_as_uint(v);
  return (u + 0x7fffu + ((u >> 16) & 1u)) >> 16;   // RNE
}

// ---------------------------------------------------------------------------
// Prep: bake fused (mask x pool-mean) weights straight into A-fragment order.
// ---------------------------------------------------------------------------
__global__ void prep_fused_weights(const float* __restrict__ w0, const float* __restrict__ b0,
                                   const float* __restrict__ w1, const float* __restrict__ b1,
                                   char* __restrict__ wsb) {
  int t = blockIdx.x * blockDim.x + threadIdx.x;
  if (t < 6720) {                       // A1: [7 g][15 k][64 lane] uint4
    int lane = t & 63;
    int r = t >> 6;
    int k = r % 15, g = r / 15;
    int m = lane & 15, h = lane >> 4;
    int pool = (m < 8) ? c_g1p[g][0] : c_g1p[g][1];
    int c = m & 7;
    int L = c_pool0_len[pool];
    float inv = 1.f / (float)L;
    uint32 us[8];
#pragma unroll
    for (int j = 0; j < 8; ++j) {
      int node = c_U1[g][2 * h + (j >> 2)];
      int ci = j & 3;
      float v = 0.f;
      if (node < 25) {
        for (int jj = 0; jj < L; ++jj) {
          int mem = c_pool0_mem[pool][jj];
          if ((c_nbm0[mem] >> node) & 1u)
            v += w0[(mem * 8 + c) * 1500 + (node * 4 + ci) * 15 + k];
        }
        v *= inv;
      }
      us[j] = f2bf(v);
    }
    uint4 o = make_uint4(us[0] | (us[1] << 16), us[2] | (us[3] << 16),
                         us[4] | (us[5] << 16), us[6] | (us[7] << 16));
    reinterpret_cast<uint4*>(wsb)[t] = o;
  } else if (t < 6720 + 13440) {        // A2: [7 p][2 ks][15 k][64 lane] uint4
    int t2 = t - 6720;
    int lane = t2 & 63;
    int r = t2 >> 6;
    int k = r % 15;
    int r2 = r / 15;
    int ks = r2 & 1, p = r2 >> 1;
    int c = lane & 15, h = lane >> 4;
    int node = c_U2[p][ks * 4 + h];
    int L = c_pool1_len[p];
    float inv = 1.f / (float)L;
    uint32 us[8];
#pragma unroll
    for (int j = 0; j < 8; ++j) {
      float v = 0.f;
      if (node < 14) {
        for (int jj = 0; jj < L; ++jj) {
          int mem = c_pool1_mem[p][jj];
          if ((c_nbm1[mem] >> node) & 1u)
            v += w1[(mem * 16 + c) * 1680 + (node * 8 + j) * 15 + k];
        }
        v *= inv;
      }
      us[j] = f2bf(v);
    }
    uint4 o = make_uint4(us[0] | (us[1] << 16), us[2] | (us[3] << 16),
                         us[4] | (us[5] << 16), us[6] | (us[7] << 16));
    reinterpret_cast<uint4*>(wsb + OFF_A2)[t2] = o;
  } else if (t < 6720 + 13440 + 112) {  // BF0
    int p = t - (6720 + 13440);
    int i = p >> 3, c = p & 7;
    int L = c_pool0_len[i];
    float v = 0.f;
    for (int jj = 0; jj < L; ++jj) v += b0[c_pool0_mem[i][jj] * 8 + c];
    reinterpret_cast<float*>(wsb + OFF_BF0)[p] = v / (float)L;
  } else if (t < 6720 + 13440 + 224) {  // BF1
    int p = t - (6720 + 13440 + 112);
    int i = p >> 4, c = p & 15;
    int L = c_pool1_len[i];
    float v = 0.f;
    for (int jj = 0; jj < L; ++jj) v += b1[c_pool1_mem[i][jj] * 16 + c];
    reinterpret_cast<float*>(wsb + OFF_BF1)[p] = v / (float)L;
  }
}

// ---------------------------------------------------------------------------
// Stage 1: 448 thr = 7 waves (wave = pool pair). t-tile 64.
// LDS [141 frames][256 B] bf16, XOR-swizzled 8B units. A prefetched (60 VGPR),
// k-loop fully unrolled. Output transposed in LDS -> y0 [b][t][112] bf16.
// launch_bounds(448,4): VGPR cap 128, 2 blocks/CU.
// ---------------------------------------------------------------------------
__global__ __launch_bounds__(448, 4) void conv_stage1(const float* __restrict__ x,
                                                      const char* __restrict__ wsb,
                                                      char* __restrict__ y0b) {
  __shared__ __align__(16) unsigned char xs[141 * 256];  // 36.1 KB
  const int tid = threadIdx.x;
  const int lane = tid & 63;
  const int g = tid >> 6;            // wave = pair index 0..6
  const int m16 = lane & 15, h = lane >> 4;
  const int b = blockIdx.y;
  const int t0 = blockIdx.x << 6;
  const int g0 = 2 * t0 - 7;

  // prefetch A fragments + bias (L2 resident) before staging
  const uint4* __restrict__ A1p = reinterpret_cast<const uint4*>(wsb) + g * 960 + lane;
  U8 a[15];
#pragma unroll
  for (int k = 0; k < 15; ++k) a[k].u = A1p[k * 64];
  const int pa = c_g1p[g][0], pb = c_g1p[g][1];
  const int chbase = (h < 2) ? (pa * 8 + 4 * h) : (pb * 8 + 4 * (h - 2));
  const float4 bv = *reinterpret_cast<const float4*>(wsb + OFF_BF0 + chbase * 4);

  // stage: frame-major, fp32 -> bf16, swizzled 8B units (q<25 data, 25-28 pad)
  const float* __restrict__ xb = x + (size_t)b * (2047 * 100);
  for (int e = tid; e < 141 * 32; e += 448) {
    int f = e >> 5, q = e & 31;
    if (q >= 29) continue;
    uint2 w = make_uint2(0u, 0u);
    int gt = g0 + f;
    if (q < 25 && (unsigned)gt < 2047u) {
      float4 v = *reinterpret_cast<const float4*>(xb + gt * 100 + 4 * q);
      w.x = f2bf(v.x) | (f2bf(v.y) << 16);
      w.y = f2bf(v.z) | (f2bf(v.w) << 16);
    }
    *reinterpret_cast<uint2*>(xs + f * 256 + ((q * 8) ^ (((f >> 1) & 7) << 3))) = w;
  }
  __syncthreads();

  const uint32 offA = (c_pk1a[g] >> (8 * h)) & 255u;
  const uint32 offB = (c_pk1b[g] >> (8 * h)) & 255u;

  f32x4 acc[4];
#pragma unroll
  for (int nt = 0; nt < 4; ++nt) acc[nt] = (f32x4)0.f;

#pragma unroll
  for (int k = 0; k < 15; ++k) {
    // frame = 2*(nt*16+m16)+k; swizzle = ((frame>>1)&7)<<3 = ((m16+(k>>1))&7)<<3
    const uint32 sw = (uint32)(((m16 + (k >> 1)) & 7) << 3);
    const uint32 a0 = offA ^ sw, a1 = offB ^ sw;
    const unsigned char* base = xs + (2 * m16 + k) * 256;
#pragma unroll
    for (int nt = 0; nt < 4; ++nt) {
      uint2 lo = *reinterpret_cast<const uint2*>(base + nt * 8192 + a0);
      uint2 hi = *reinterpret_cast<const uint2*>(base + nt * 8192 + a1);
      U8 bfr; bfr.u = make_uint4(lo.x, lo.y, hi.x, hi.y);
      acc[nt] = __builtin_amdgcn_mfma_f32_16x16x32_bf16(a[k].s, bfr.s, acc[nt], 0, 0, 0);
    }
  }

  // epilogue: bias+relu, pack bf16, swizzled transpose via LDS, coalesced store
  __syncthreads();   // all LDS reads done before overwrite
#pragma unroll
  for (int nt = 0; nt < 4; ++nt) {
    float o0 = fmaxf(acc[nt][0] + bv.x, 0.f);
    float o1 = fmaxf(acc[nt][1] + bv.y, 0.f);
    float o2 = fmaxf(acc[nt][2] + bv.z, 0.f);
    float o3 = fmaxf(acc[nt][3] + bv.w, 0.f);
    uint2 wpk = make_uint2(f2bf(o0) | (f2bf(o1) << 16), f2bf(o2) | (f2bf(o3) << 16));
    int row = nt * 16 + m16;
    *reinterpret_cast<uint2*>(xs + row * 256 + ((chbase * 2) ^ ((row & 7) << 3))) = wpk;
  }
  __syncthreads();
  for (int e = tid; e < 1024; e += 448) {
    int row = e >> 4, q = e & 15;
    if (q >= 14) continue;
    uint32 sw = (uint32)((row & 7) << 3);
    uint2 av = *reinterpret_cast<const uint2*>(xs + row * 256 + ((q * 16) ^ sw));
    uint2 dv = *reinterpret_cast<const uint2*>(xs + row * 256 + ((q * 16 + 8) ^ sw));
    *reinterpret_cast<uint4*>(y0b + (size_t)(b * 1024 + t0 + row) * 224 + q * 16) =
        make_uint4(av.x, av.y, dv.x, dv.y);
  }
}

// ---------------------------------------------------------------------------
// Stage 2: 448 thr = 7 waves (wave = pool). t-tile 32, LDS [80 rows][256 B]
// bf16 (parity-split rows, 16B XOR swizzle). A prefetched in two 15-frag
// halves (fits 128-VGPR cap), fully unrolled. launch_bounds(448,4).
// ---------------------------------------------------------------------------
__global__ __launch_bounds__(448, 4) void conv_stage2(const char* __restrict__ wsb,
                                                      const char* __restrict__ y0b,
                                                      float* __restrict__ out) {
  __shared__ __align__(16) unsigned char xs[80 * 256];  // 20.5 KB
  const int tid = threadIdx.x;
  const int lane = tid & 63;
  const int p = tid >> 6;           // wave = pool 0..6
  const int m16 = lane & 15, h = lane >> 4;
  const int b = blockIdx.y;
  const int t0 = blockIdx.x << 5;
  const int g0 = 2 * t0 - 7;

  const uint4* __restrict__ A2p = reinterpret_cast<const uint4*>(wsb + OFF_A2) + p * 1920 + lane;
  const float4 bv = *reinterpret_cast<const float4*>(wsb + OFF_BF1 + (p * 16 + 4 * h) * 4);

  // prefetch ks=0 half (15 frags = 60 VGPR) before staging
  U8 a[15];
#pragma unroll
  for (int k = 0; k < 15; ++k) a[k].u = A2p[k * 64];

  // stage: row copy y0[t][112] -> LDS [pr][256B] (q=14,15 zero pad nodes)
  const char* __restrict__ yb = y0b + (size_t)b * (1024 * 224);
  for (int e = tid; e < 77 * 16; e += 448) {
    int f = e >> 4, q = e & 15;
    uint4 v = make_uint4(0u, 0u, 0u, 0u);
    int gt = g0 + f;
    if (q < 14 && (unsigned)gt < 1024u)
      v = *reinterpret_cast<const uint4*>(yb + (size_t)gt * 224 + q * 16);
    int pr = (f >> 1) + (f & 1) * 40;
    *reinterpret_cast<uint4*>(xs + pr * 256 + ((q * 16) ^ ((pr & 7) << 4))) = v;
  }
  __syncthreads();

  f32x4 acc[2];
  acc[0] = (f32x4)0.f; acc[1] = (f32x4)0.f;
  const uint32 mbase = (uint32)(m16 * 256);

  // ---- ks = 0 ----
  {
    const uint32 noff = (c_pk2[p][0] >> (8 * h)) & 255u;
#pragma unroll
    for (int k = 0; k < 15; ++k) {
      const uint32 sw = (uint32)(((m16 + (k >> 1)) & 7) << 4);
      const uint32 ab = mbase + (noff ^ sw);
      const int imm = ((k >> 1) + (k & 1) * 40) * 256;
      U8 b0f, b1f;
      b0f.u = *reinterpret_cast<const uint4*>(xs + ab + imm);
      b1f.u = *reinterpret_cast<const uint4*>(xs + ab + imm + 4096);
      acc[0] = __builtin_amdgcn_mfma_f32_16x16x32_bf16(a[k].s, b0f.s, acc[0], 0, 0, 0);
      acc[1] = __builtin_amdgcn_mfma_f32_16x16x32_bf16(a[k].s, b1f.s, acc[1], 0, 0, 0);
    }
  }
  // load ks=1 fragments (reuses a[] registers)
#pragma unroll
  for (int k = 0; k < 15; ++k) a[k].u = A2p[(15 + k) * 64];
  // ---- ks = 1 ----
  {
    const uint32 noff = (c_pk2[p][1] >> (8 * h)) & 255u;
#pragma unroll
    for (int k = 0; k < 15; ++k) {
      const uint32 sw = (uint32)(((m16 + (k >> 1)) & 7) << 4);
      const uint32 ab = mbase + (noff ^ sw);
      const int imm = ((k >> 1) + (k & 1) * 40) * 256;
      U8 b0f, b1f;
      b0f.u = *reinterpret_cast<const uint4*>(xs + ab + imm);
      b1f.u = *reinterpret_cast<const uint4*>(xs + ab + imm + 4096);
      acc[0] = __builtin_amdgcn_mfma_f32_16x16x32_bf16(a[k].s, b0f.s, acc[0], 0, 0, 0);
      acc[1] = __builtin_amdgcn_mfma_f32_16x16x32_bf16(a[k].s, b1f.s, acc[1], 0, 0, 0);
    }
  }

#pragma unroll
  for (int nt = 0; nt < 2; ++nt) {
    size_t obase = ((size_t)b * 112 + p * 16 + 4 * h) * 512 + t0 + nt * 16 + m16;
    out[obase]        = fmaxf(acc[nt][0] + bv.x, 0.f);
    out[obase + 512]  = fmaxf(acc[nt][1] + bv.y, 0.f);
    out[obase + 1024] = fmaxf(acc[nt][2] + bv.z, 0.f);
    out[obase + 1536] = fmaxf(acc[nt][3] + bv.w, 0.f);
  }
}

extern "C" void kernel_launch(void* const* d_in, const int* in_sizes, int n_in,
                              void* d_out, int out_size, void* d_ws, size_t ws_size,
                              hipStream_t stream) {
  const float* x  = (const float*)d_in[0];
  const float* w0 = (const float*)d_in[1];
  const float* b0 = (const float*)d_in[2];
  const float* w1 = (const float*)d_in[3];
  const float* b1 = (const float*)d_in[4];
  char* wsb = (char*)d_ws;
  float* out = (float*)d_out;

  prep_fused_weights<<<80, 256, 0, stream>>>(w0, b0, w1, b1, wsb);
  conv_stage1<<<dim3(16, 64), 448, 0, stream>>>(x, wsb, wsb + OFF_Y0);
  conv_stage2<<<dim3(16, 64), 448, 0, stream>>>(wsb, wsb + OFF_Y0, out);
}

// Round 6
// 54.448 us; speedup vs baseline: 1.9816x; 1.1346x over previous
//
#include <hip/hip_runtime.h>

// ---------------------------------------------------------------------------
// DynamicEncoder via MFMA (gfx950, mfma_f32_16x16x32_bf16).
//
// Round 6: (a) staging split into gather-to-regs then convert+ds_write
// (removes ~10x serial HBM-latency chain per thread); (b) stage1 LDS swizzle
// widened 3->4 bits (&15, full 128B bank window) -- per-16-lane-phase
// bijective => zero bank conflicts on B-reads (R5 had 3.55M @ 6-way).
//
// Stage1: x (64, 2047(+1 zero), 100ch) -> y0 bf16 [b][1024 t][112 ch]
//   7 pool-PAIRS, union <= 8 nodes x 4 ci = 32 cin = one K-step, 15 taps.
// Stage2: y0 -> out fp32 (64, 112, 512); 7 pools, union <= 64 cin = 2 K-steps.
//
// Workspace (bytes):
//   A1  @ 0      : [7 g][15 k][64 lane][8] bf16 = 107520
//   A2  @ 107520 : [7 p][2 ks][15 k][64][8] bf16 = 215040
//   BF0 @ 322560 : 112 f32 ; BF1 @ 323008 : 112 f32
//   Y0  @ 323584 : [64 b][1024 t][112 ch] bf16 = 14680064
// ---------------------------------------------------------------------------

#define OFF_A2  107520u
#define OFF_BF0 322560u
#define OFF_BF1 323008u
#define OFF_Y0  323584u

typedef unsigned int uint32;
typedef __attribute__((ext_vector_type(8))) short bs8;
typedef __attribute__((ext_vector_type(4))) float f32x4;
union U8 { uint4 u; bs8 s; };

// ---- graph constants (verified rounds 1-3) ----
__constant__ int c_pool0_len[14] = {2,2,2,2,1,2,2,1,2,2,1,2,2,2};
__constant__ int c_pool0_mem[14][2] = {{0,3},{6,9},{1,4},{7,10},{2,2},{5,8},{11,14},{12,12},
                                       {15,17},{19,21},{13,13},{16,18},{20,22},{23,24}};
__constant__ unsigned c_nbm0[25] = {
 0x180000Fu,0x1800017u,0x1800027u,0x1800049u,0x92u,0x124u,0x248u,0x490u,
 0x3920u,0x240u,0x480u,0x7900u,0xB900u,0x13900u,0x4800u,0x29000u,
 0x52000u,0xA8000u,0x150000u,0x2A0000u,0x540000u,0x280000u,0x500000u,
 0x180000Fu,0x180000Fu
};
__constant__ int c_pool1_len[7] = {2,2,2,1,3,3,1};
__constant__ int c_pool1_mem[7][3] = {{0,1,1},{2,3,3},{4,5,5},{6,6,6},{7,8,9},{10,11,12},{13,13,13}};
__constant__ unsigned c_nbm1[14] = {
 0x2017u,0x2003u,0x201Du,0xCu,0x2035u,0x4F0u,0x4E0u,0x5E0u,
 0x380u,0x300u,0xCE0u,0x1C00u,0x1800u,0x2017u
};
// stage1 pool pairs and their combined unions (pad node 25 = zero channels)
__constant__ int c_g1p[7][2] = {{0,13},{1,3},{2,4},{5,6},{7,10},{8,11},{9,12}};
__constant__ int c_U1[7][8] = {
 {0,1,2,3,6,23,24,25},
 {3,4,6,7,9,10,25,25},
 {0,1,2,4,5,7,23,24},
 {2,5,8,11,12,13,14,25},
 {8,11,12,13,15,16,25,25},
 {12,13,15,16,17,18,19,20},
 {17,18,19,20,21,22,25,25}};
// stage2 unions (pad node 14 = zero channels)
__constant__ int c_U2[7][8] = {
 {0,1,2,4,13,14,14,14},
 {0,2,3,4,13,14,14,14},
 {0,2,4,5,6,7,10,13},
 {5,6,7,10,14,14,14,14},
 {5,6,7,8,9,10,14,14},
 {5,6,7,10,11,12,14,14},
 {0,1,2,4,13,14,14,14}};
// packed per-lane-group LDS byte offsets (node*8 stage1, node*16 stage2)
__constant__ unsigned c_pk1a[7] = {0xC0301000u,0xC8483018u,0xB8281000u,0x70604010u,
                                   0xC8786040u,0x98887860u,0xC8A89888u};
__constant__ unsigned c_pk1b[7] = {0xC8B81808u,0xC8503820u,0xC0382008u,0xC8685828u,
                                   0xC8806858u,0xA0908068u,0xC8B0A090u};
__constant__ unsigned c_pk2[7][2] = {
 {0x40201000u,0xE0E0E0D0u},{0x40302000u,0xE0E0E0D0u},{0x50402000u,0xD0A07060u},
 {0xA0706050u,0xE0E0E0E0u},{0x80706050u,0xE0E0A090u},{0xA0706050u,0xE0E0C0B0u},
 {0x40201000u,0xE0E0E0D0u}};

__device__ __forceinline__ uint32 f2bf(float v) {
  uint32 u = __float_as_uint(v);
  return (u + 0x7fffu + ((u >> 16) & 1u)) >> 16;   // RNE
}

// ---------------------------------------------------------------------------
// Prep: bake fused (mask x pool-mean) weights straight into A-fragment order.
// ---------------------------------------------------------------------------
__global__ void prep_fused_weights(const float* __restrict__ w0, const float* __restrict__ b0,
                                   const float* __restrict__ w1, const float* __restrict__ b1,
                                   char* __restrict__ wsb) {
  int t = blockIdx.x * blockDim.x + threadIdx.x;
  if (t < 6720) {                       // A1: [7 g][15 k][64 lane] uint4
    int lane = t & 63;
    int r = t >> 6;
    int k = r % 15, g = r / 15;
    int m = lane & 15, h = lane >> 4;
    int pool = (m < 8) ? c_g1p[g][0] : c_g1p[g][1];
    int c = m & 7;
    int L = c_pool0_len[pool];
    float inv = 1.f / (float)L;
    uint32 us[8];
#pragma unroll
    for (int j = 0; j < 8; ++j) {
      int node = c_U1[g][2 * h + (j >> 2)];
      int ci = j & 3;
      float v = 0.f;
      if (node < 25) {
        for (int jj = 0; jj < L; ++jj) {
          int mem = c_pool0_mem[pool][jj];
          if ((c_nbm0[mem] >> node) & 1u)
            v += w0[(mem * 8 + c) * 1500 + (node * 4 + ci) * 15 + k];
        }
        v *= inv;
      }
      us[j] = f2bf(v);
    }
    uint4 o = make_uint4(us[0] | (us[1] << 16), us[2] | (us[3] << 16),
                         us[4] | (us[5] << 16), us[6] | (us[7] << 16));
    reinterpret_cast<uint4*>(wsb)[t] = o;
  } else if (t < 6720 + 13440) {        // A2: [7 p][2 ks][15 k][64 lane] uint4
    int t2 = t - 6720;
    int lane = t2 & 63;
    int r = t2 >> 6;
    int k = r % 15;
    int r2 = r / 15;
    int ks = r2 & 1, p = r2 >> 1;
    int c = lane & 15, h = lane >> 4;
    int node = c_U2[p][ks * 4 + h];
    int L = c_pool1_len[p];
    float inv = 1.f / (float)L;
    uint32 us[8];
#pragma unroll
    for (int j = 0; j < 8; ++j) {
      float v = 0.f;
      if (node < 14) {
        for (int jj = 0; jj < L; ++jj) {
          int mem = c_pool1_mem[p][jj];
          if ((c_nbm1[mem] >> node) & 1u)
            v += w1[(mem * 16 + c) * 1680 + (node * 8 + j) * 15 + k];
        }
        v *= inv;
      }
      us[j] = f2bf(v);
    }
    uint4 o = make_uint4(us[0] | (us[1] << 16), us[2] | (us[3] << 16),
                         us[4] | (us[5] << 16), us[6] | (us[7] << 16));
    reinterpret_cast<uint4*>(wsb + OFF_A2)[t2] = o;
  } else if (t < 6720 + 13440 + 112) {  // BF0
    int p = t - (6720 + 13440);
    int i = p >> 3, c = p & 7;
    int L = c_pool0_len[i];
    float v = 0.f;
    for (int jj = 0; jj < L; ++jj) v += b0[c_pool0_mem[i][jj] * 8 + c];
    reinterpret_cast<float*>(wsb + OFF_BF0)[p] = v / (float)L;
  } else if (t < 6720 + 13440 + 224) {  // BF1
    int p = t - (6720 + 13440 + 112);
    int i = p >> 4, c = p & 15;
    int L = c_pool1_len[i];
    float v = 0.f;
    for (int jj = 0; jj < L; ++jj) v += b1[c_pool1_mem[i][jj] * 16 + c];
    reinterpret_cast<float*>(wsb + OFF_BF1)[p] = v / (float)L;
  }
}

// ---------------------------------------------------------------------------
// Stage 1: 448 thr = 7 waves (wave = pool pair). t-tile 64.
// LDS [141 frames][256 B] bf16, 4-bit XOR swizzle on 8B units (phase-bijective
// => conflict-free). Gather-then-write staging; A prefetched between phases.
// launch_bounds(448,4): VGPR cap 128, 2 blocks/CU.
// ---------------------------------------------------------------------------
__global__ __launch_bounds__(448, 4) void conv_stage1(const float* __restrict__ x,
                                                      const char* __restrict__ wsb,
                                                      char* __restrict__ y0b) {
  __shared__ __align__(16) unsigned char xs[141 * 256];  // 36.1 KB
  const int tid = threadIdx.x;
  const int lane = tid & 63;
  const int g = tid >> 6;            // wave = pair index 0..6
  const int m16 = lane & 15, h = lane >> 4;
  const int b = blockIdx.y;
  const int t0 = blockIdx.x << 6;
  const int g0 = 2 * t0 - 7;

  // ---- staging phase A: issue ALL global loads into registers ----
  const float* __restrict__ xb = x + (size_t)b * (2047 * 100);
  float4 rg[11];
#pragma unroll
  for (int i = 0; i < 11; ++i) {
    rg[i] = make_float4(0.f, 0.f, 0.f, 0.f);
    if (i < 10 || tid < 32) {
      int e = tid + i * 448;
      int f = e >> 5, q = e & 31;
      int gt = g0 + f;
      if (q < 25 && (unsigned)gt < 2047u)
        rg[i] = *reinterpret_cast<const float4*>(xb + gt * 100 + 4 * q);
    }
  }

  // A-fragment + bias prefetch (L2 resident) — issued while staging loads fly
  const uint4* __restrict__ A1p = reinterpret_cast<const uint4*>(wsb) + g * 960 + lane;
  U8 a[15];
#pragma unroll
  for (int k = 0; k < 15; ++k) a[k].u = A1p[k * 64];
  const int pa = c_g1p[g][0], pb = c_g1p[g][1];
  const int chbase = (h < 2) ? (pa * 8 + 4 * h) : (pb * 8 + 4 * (h - 2));
  const float4 bv = *reinterpret_cast<const float4*>(wsb + OFF_BF0 + chbase * 4);

  // ---- staging phase B: convert + swizzled ds_write ----
#pragma unroll
  for (int i = 0; i < 11; ++i) {
    if (i == 10 && tid >= 32) continue;
    int e = tid + i * 448;
    int f = e >> 5, q = e & 31;
    if (q >= 29) continue;
    uint2 w = make_uint2(f2bf(rg[i].x) | (f2bf(rg[i].y) << 16),
                         f2bf(rg[i].z) | (f2bf(rg[i].w) << 16));
    *reinterpret_cast<uint2*>(xs + f * 256 + ((q * 8) ^ (((f >> 1) & 15) << 3))) = w;
  }
  __syncthreads();

  const uint32 offA = (c_pk1a[g] >> (8 * h)) & 255u;
  const uint32 offB = (c_pk1b[g] >> (8 * h)) & 255u;

  f32x4 acc[4];
#pragma unroll
  for (int nt = 0; nt < 4; ++nt) acc[nt] = (f32x4)0.f;

#pragma unroll
  for (int k = 0; k < 15; ++k) {
    // frame = 2*(nt*16+m16)+k; swizzle = ((frame>>1)&15)<<3 = ((m16+(k>>1))&15)<<3
    const uint32 sw = (uint32)(((m16 + (k >> 1)) & 15) << 3);
    const uint32 a0 = offA ^ sw, a1 = offB ^ sw;
    const unsigned char* base = xs + (2 * m16 + k) * 256;
#pragma unroll
    for (int nt = 0; nt < 4; ++nt) {
      uint2 lo = *reinterpret_cast<const uint2*>(base + nt * 8192 + a0);
      uint2 hi = *reinterpret_cast<const uint2*>(base + nt * 8192 + a1);
      U8 bfr; bfr.u = make_uint4(lo.x, lo.y, hi.x, hi.y);
      acc[nt] = __builtin_amdgcn_mfma_f32_16x16x32_bf16(a[k].s, bfr.s, acc[nt], 0, 0, 0);
    }
  }

  // epilogue: bias+relu, pack bf16, swizzled transpose via LDS, coalesced store
  __syncthreads();   // all LDS reads done before overwrite
#pragma unroll
  for (int nt = 0; nt < 4; ++nt) {
    float o0 = fmaxf(acc[nt][0] + bv.x, 0.f);
    float o1 = fmaxf(acc[nt][1] + bv.y, 0.f);
    float o2 = fmaxf(acc[nt][2] + bv.z, 0.f);
    float o3 = fmaxf(acc[nt][3] + bv.w, 0.f);
    uint2 wpk = make_uint2(f2bf(o0) | (f2bf(o1) << 16), f2bf(o2) | (f2bf(o3) << 16));
    int row = nt * 16 + m16;
    *reinterpret_cast<uint2*>(xs + row * 256 + ((chbase * 2) ^ ((row & 15) << 3))) = wpk;
  }
  __syncthreads();
  for (int e = tid; e < 1024; e += 448) {
    int row = e >> 4, q = e & 15;
    if (q >= 14) continue;
    uint32 sw = (uint32)((row & 15) << 3);
    uint2 av = *reinterpret_cast<const uint2*>(xs + row * 256 + ((q * 16) ^ sw));
    uint2 dv = *reinterpret_cast<const uint2*>(xs + row * 256 + ((q * 16 + 8) ^ sw));
    *reinterpret_cast<uint4*>(y0b + (size_t)(b * 1024 + t0 + row) * 224 + q * 16) =
        make_uint4(av.x, av.y, dv.x, dv.y);
  }
}

// ---------------------------------------------------------------------------
// Stage 2: 448 thr = 7 waves (wave = pool). t-tile 32, LDS [80 rows][256 B]
// bf16 (parity-split rows, 16B XOR swizzle). Gather-then-write staging;
// A prefetched in two 15-frag halves. launch_bounds(448,4).
// ---------------------------------------------------------------------------
__global__ __launch_bounds__(448, 4) void conv_stage2(const char* __restrict__ wsb,
                                                      const char* __restrict__ y0b,
                                                      float* __restrict__ out) {
  __shared__ __align__(16) unsigned char xs[80 * 256];  // 20.5 KB
  const int tid = threadIdx.x;
  const int lane = tid & 63;
  const int p = tid >> 6;           // wave = pool 0..6
  const int m16 = lane & 15, h = lane >> 4;
  const int b = blockIdx.y;
  const int t0 = blockIdx.x << 5;
  const int g0 = 2 * t0 - 7;

  // ---- staging phase A: issue all global loads into registers ----
  const char* __restrict__ yb = y0b + (size_t)b * (1024 * 224);
  uint4 rg[3];
#pragma unroll
  for (int i = 0; i < 3; ++i) {
    rg[i] = make_uint4(0u, 0u, 0u, 0u);
    if (i < 2 || tid < 336) {
      int e = tid + i * 448;
      int f = e >> 4, q = e & 15;
      int gt = g0 + f;
      if (q < 14 && (unsigned)gt < 1024u)
        rg[i] = *reinterpret_cast<const uint4*>(yb + (size_t)gt * 224 + q * 16);
    }
  }

  // prefetch ks=0 A-half + bias while staging loads fly
  const uint4* __restrict__ A2p = reinterpret_cast<const uint4*>(wsb + OFF_A2) + p * 1920 + lane;
  U8 a[15];
#pragma unroll
  for (int k = 0; k < 15; ++k) a[k].u = A2p[k * 64];
  const float4 bv = *reinterpret_cast<const float4*>(wsb + OFF_BF1 + (p * 16 + 4 * h) * 4);

  // ---- staging phase B: swizzled ds_write ----
#pragma unroll
  for (int i = 0; i < 3; ++i) {
    if (i == 2 && tid >= 336) continue;
    int e = tid + i * 448;
    int f = e >> 4, q = e & 15;
    int pr = (f >> 1) + (f & 1) * 40;
    *reinterpret_cast<uint4*>(xs + pr * 256 + ((q * 16) ^ ((pr & 7) << 4))) = rg[i];
  }
  __syncthreads();

  f32x4 acc[2];
  acc[0] = (f32x4)0.f; acc[1] = (f32x4)0.f;
  const uint32 mbase = (uint32)(m16 * 256);

  // ---- ks = 0 ----
  {
    const uint32 noff = (c_pk2[p][0] >> (8 * h)) & 255u;
#pragma unroll
    for (int k = 0; k < 15; ++k) {
      const uint32 sw = (uint32)(((m16 + (k >> 1)) & 7) << 4);
      const uint32 ab = mbase + (noff ^ sw);
      const int imm = ((k >> 1) + (k & 1) * 40) * 256;
      U8 b0f, b1f;
      b0f.u = *reinterpret_cast<const uint4*>(xs + ab + imm);
      b1f.u = *reinterpret_cast<const uint4*>(xs + ab + imm + 4096);
      acc[0] = __builtin_amdgcn_mfma_f32_16x16x32_bf16(a[k].s, b0f.s, acc[0], 0, 0, 0);
      acc[1] = __builtin_amdgcn_mfma_f32_16x16x32_bf16(a[k].s, b1f.s, acc[1], 0, 0, 0);
    }
  }
  // load ks=1 fragments (reuses a[] registers)
#pragma unroll
  for (int k = 0; k < 15; ++k) a[k].u = A2p[(15 + k) * 64];
  // ---- ks = 1 ----
  {
    const uint32 noff = (c_pk2[p][1] >> (8 * h)) & 255u;
#pragma unroll
    for (int k = 0; k < 15; ++k) {
      const uint32 sw = (uint32)(((m16 + (k >> 1)) & 7) << 4);
      const uint32 ab = mbase + (noff ^ sw);
      const int imm = ((k >> 1) + (k & 1) * 40) * 256;
      U8 b0f, b1f;
      b0f.u = *reinterpret_cast<const uint4*>(xs + ab + imm);
      b1f.u = *reinterpret_cast<const uint4*>(xs + ab + imm + 4096);
      acc[0] = __builtin_amdgcn_mfma_f32_16x16x32_bf16(a[k].s, b0f.s, acc[0], 0, 0, 0);
      acc[1] = __builtin_amdgcn_mfma_f32_16x16x32_bf16(a[k].s, b1f.s, acc[1], 0, 0, 0);
    }
  }

#pragma unroll
  for (int nt = 0; nt < 2; ++nt) {
    size_t obase = ((size_t)b * 112 + p * 16 + 4 * h) * 512 + t0 + nt * 16 + m16;
    out[obase]        = fmaxf(acc[nt][0] + bv.x, 0.f);
    out[obase + 512]  = fmaxf(acc[nt][1] + bv.y, 0.f);
    out[obase + 1024] = fmaxf(acc[nt][2] + bv.z, 0.f);
    out[obase + 1536] = fmaxf(acc[nt][3] + bv.w, 0.f);
  }
}

extern "C" void kernel_launch(void* const* d_in, const int* in_sizes, int n_in,
                              void* d_out, int out_size, void* d_ws, size_t ws_size,
                              hipStream_t stream) {
  const float* x  = (const float*)d_in[0];
  const float* w0 = (const float*)d_in[1];
  const float* b0 = (const float*)d_in[2];
  const float* w1 = (const float*)d_in[3];
  const float* b1 = (const float*)d_in[4];
  char* wsb = (char*)d_ws;
  float* out = (float*)d_out;

  prep_fused_weights<<<80, 256, 0, stream>>>(w0, b0, w1, b1, wsb);
  conv_stage1<<<dim3(16, 64), 448, 0, stream>>>(x, wsb, wsb + OFF_Y0);
  conv_stage2<<<dim3(16, 64), 448, 0, stream>>>(wsb, wsb + OFF_Y0, out);
}

// Round 7
// 53.725 us; speedup vs baseline: 2.0083x; 1.0135x over previous
//
#include <hip/hip_runtime.h>

// ---------------------------------------------------------------------------
// DynamicEncoder via MFMA (gfx950, mfma_f32_16x16x32_bf16) — FUSED.
//
// Round 7: single kernel does stage1+stage2; the y0 tile lives in LDS only
// (halo recomputed: 32 out frames <- 77 y0 frames <- 173 x frames). Kills the
// y0 HBM round-trip (~33 MB), the 2nd kernel's gather-latency ramp, and one
// launch. xs: [173][256B] bf16, 8B-unit XOR swizzle ((f>>1)&15)<<3.
// ys: [80][256B] bf16, 16B-unit XOR swizzle ((row>>1)&7)<<4 (write==read).
// LDS 63.3 KB -> 2 blocks/CU. A-frags loaded AFTER staging writes (VGPR<128).
//
// Workspace (bytes):
//   A1  @ 0      : [7 g][15 k][64 lane][8] bf16 = 107520
//   A2  @ 107520 : [7 p][2 ks][15 k][64][8] bf16 = 215040
//   BF0 @ 322560 : 112 f32 ; BF1 @ 323008 : 112 f32
// ---------------------------------------------------------------------------

#define OFF_A2  107520u
#define OFF_BF0 322560u
#define OFF_BF1 323008u

typedef unsigned int uint32;
typedef __attribute__((ext_vector_type(8))) short bs8;
typedef __attribute__((ext_vector_type(4))) float f32x4;
union U8 { uint4 u; bs8 s; };

// ---- graph constants (verified rounds 1-6) ----
__constant__ int c_pool0_len[14] = {2,2,2,2,1,2,2,1,2,2,1,2,2,2};
__constant__ int c_pool0_mem[14][2] = {{0,3},{6,9},{1,4},{7,10},{2,2},{5,8},{11,14},{12,12},
                                       {15,17},{19,21},{13,13},{16,18},{20,22},{23,24}};
__constant__ unsigned c_nbm0[25] = {
 0x180000Fu,0x1800017u,0x1800027u,0x1800049u,0x92u,0x124u,0x248u,0x490u,
 0x3920u,0x240u,0x480u,0x7900u,0xB900u,0x13900u,0x4800u,0x29000u,
 0x52000u,0xA8000u,0x150000u,0x2A0000u,0x540000u,0x280000u,0x500000u,
 0x180000Fu,0x180000Fu
};
__constant__ int c_pool1_len[7] = {2,2,2,1,3,3,1};
__constant__ int c_pool1_mem[7][3] = {{0,1,1},{2,3,3},{4,5,5},{6,6,6},{7,8,9},{10,11,12},{13,13,13}};
__constant__ unsigned c_nbm1[14] = {
 0x2017u,0x2003u,0x201Du,0xCu,0x2035u,0x4F0u,0x4E0u,0x5E0u,
 0x380u,0x300u,0xCE0u,0x1C00u,0x1800u,0x2017u
};
__constant__ int c_g1p[7][2] = {{0,13},{1,3},{2,4},{5,6},{7,10},{8,11},{9,12}};
__constant__ int c_U1[7][8] = {
 {0,1,2,3,6,23,24,25},
 {3,4,6,7,9,10,25,25},
 {0,1,2,4,5,7,23,24},
 {2,5,8,11,12,13,14,25},
 {8,11,12,13,15,16,25,25},
 {12,13,15,16,17,18,19,20},
 {17,18,19,20,21,22,25,25}};
__constant__ int c_U2[7][8] = {
 {0,1,2,4,13,14,14,14},
 {0,2,3,4,13,14,14,14},
 {0,2,4,5,6,7,10,13},
 {5,6,7,10,14,14,14,14},
 {5,6,7,8,9,10,14,14},
 {5,6,7,10,11,12,14,14},
 {0,1,2,4,13,14,14,14}};
__constant__ unsigned c_pk1a[7] = {0xC0301000u,0xC8483018u,0xB8281000u,0x70604010u,
                                   0xC8786040u,0x98887860u,0xC8A89888u};
__constant__ unsigned c_pk1b[7] = {0xC8B81808u,0xC8503820u,0xC0382008u,0xC8685828u,
                                   0xC8806858u,0xA0908068u,0xC8B0A090u};
__constant__ unsigned c_pk2[7][2] = {
 {0x40201000u,0xE0E0E0D0u},{0x40302000u,0xE0E0E0D0u},{0x50402000u,0xD0A07060u},
 {0xA0706050u,0xE0E0E0E0u},{0x80706050u,0xE0E0A090u},{0xA0706050u,0xE0E0C0B0u},
 {0x40201000u,0xE0E0E0D0u}};

__device__ __forceinline__ uint32 f2bf(float v) {
  uint32 u = __float_as_uint(v);
  return (u + 0x7fffu + ((u >> 16) & 1u)) >> 16;   // RNE
}

// ---------------------------------------------------------------------------
// Prep: bake fused (mask x pool-mean) weights straight into A-fragment order.
// ---------------------------------------------------------------------------
__global__ void prep_fused_weights(const float* __restrict__ w0, const float* __restrict__ b0,
                                   const float* __restrict__ w1, const float* __restrict__ b1,
                                   char* __restrict__ wsb) {
  int t = blockIdx.x * blockDim.x + threadIdx.x;
  if (t < 6720) {                       // A1: [7 g][15 k][64 lane] uint4
    int lane = t & 63;
    int r = t >> 6;
    int k = r % 15, g = r / 15;
    int m = lane & 15, h = lane >> 4;
    int pool = (m < 8) ? c_g1p[g][0] : c_g1p[g][1];
    int c = m & 7;
    int L = c_pool0_len[pool];
    float inv = 1.f / (float)L;
    uint32 us[8];
#pragma unroll
    for (int j = 0; j < 8; ++j) {
      int node = c_U1[g][2 * h + (j >> 2)];
      int ci = j & 3;
      float v = 0.f;
      if (node < 25) {
        for (int jj = 0; jj < L; ++jj) {
          int mem = c_pool0_mem[pool][jj];
          if ((c_nbm0[mem] >> node) & 1u)
            v += w0[(mem * 8 + c) * 1500 + (node * 4 + ci) * 15 + k];
        }
        v *= inv;
      }
      us[j] = f2bf(v);
    }
    uint4 o = make_uint4(us[0] | (us[1] << 16), us[2] | (us[3] << 16),
                         us[4] | (us[5] << 16), us[6] | (us[7] << 16));
    reinterpret_cast<uint4*>(wsb)[t] = o;
  } else if (t < 6720 + 13440) {        // A2: [7 p][2 ks][15 k][64 lane] uint4
    int t2 = t - 6720;
    int lane = t2 & 63;
    int r = t2 >> 6;
    int k = r % 15;
    int r2 = r / 15;
    int ks = r2 & 1, p = r2 >> 1;
    int c = lane & 15, h = lane >> 4;
    int node = c_U2[p][ks * 4 + h];
    int L = c_pool1_len[p];
    float inv = 1.f / (float)L;
    uint32 us[8];
#pragma unroll
    for (int j = 0; j < 8; ++j) {
      float v = 0.f;
      if (node < 14) {
        for (int jj = 0; jj < L; ++jj) {
          int mem = c_pool1_mem[p][jj];
          if ((c_nbm1[mem] >> node) & 1u)
            v += w1[(mem * 16 + c) * 1680 + (node * 8 + j) * 15 + k];
        }
        v *= inv;
      }
      us[j] = f2bf(v);
    }
    uint4 o = make_uint4(us[0] | (us[1] << 16), us[2] | (us[3] << 16),
                         us[4] | (us[5] << 16), us[6] | (us[7] << 16));
    reinterpret_cast<uint4*>(wsb + OFF_A2)[t2] = o;
  } else if (t < 6720 + 13440 + 112) {  // BF0
    int p = t - (6720 + 13440);
    int i = p >> 3, c = p & 7;
    int L = c_pool0_len[i];
    float v = 0.f;
    for (int jj = 0; jj < L; ++jj) v += b0[c_pool0_mem[i][jj] * 8 + c];
    reinterpret_cast<float*>(wsb + OFF_BF0)[p] = v / (float)L;
  } else if (t < 6720 + 13440 + 224) {  // BF1
    int p = t - (6720 + 13440 + 112);
    int i = p >> 4, c = p & 15;
    int L = c_pool1_len[i];
    float v = 0.f;
    for (int jj = 0; jj < L; ++jj) v += b1[c_pool1_mem[i][jj] * 16 + c];
    reinterpret_cast<float*>(wsb + OFF_BF1)[p] = v / (float)L;
  }
}

// ---------------------------------------------------------------------------
// Fused conv: block = (32 out frames, batch). 448 thr = 7 waves.
// Wave g: stage1 pool-pair g (5 nt of 16 y0 rows), then stage2 pool g.
// ---------------------------------------------------------------------------
__global__ __launch_bounds__(448, 4) void conv_fused(const float* __restrict__ x,
                                                     const char* __restrict__ wsb,
                                                     float* __restrict__ out) {
  __shared__ __align__(16) unsigned char xs[173 * 256];  // 44.3 KB, x tile
  __shared__ __align__(16) unsigned char ys[80 * 256];   // 20.0 KB, y0 tile
  const int tid = threadIdx.x;
  const int lane = tid & 63;
  const int g = tid >> 6;            // wave index = pool-pair (s1) = pool (s2)
  const int m16 = lane & 15, h = lane >> 4;
  const int b = blockIdx.y;
  const int t0 = blockIdx.x << 5;    // 32 output frames per block
  const int f0y = 2 * t0 - 7;        // ys row r <-> y0 frame f0y + r
  const int g0x = 4 * t0 - 21;       // xs row f <-> x frame g0x + f

  // ---- gather x tile: issue ALL loads, then convert+swizzled ds_write ----
  const float* __restrict__ xb = x + (size_t)b * (2047 * 100);
  float4 rg[10];
#pragma unroll
  for (int i = 0; i < 10; ++i) {
    rg[i] = make_float4(0.f, 0.f, 0.f, 0.f);
    int e = tid + i * 448;
    if (e < 4325) {                       // 173 frames x 25 float4
      int f = e / 25, q = e - f * 25;
      int gt = g0x + f;
      if ((unsigned)gt < 2047u)
        rg[i] = *reinterpret_cast<const float4*>(xb + gt * 100 + 4 * q);
    }
  }
  // zero pad-node unit (bytes 200..207) of each x row
  for (int e = tid; e < 173; e += 448)
    *reinterpret_cast<uint2*>(xs + e * 256 + (200u ^ (((e >> 1) & 15) << 3))) =
        make_uint2(0u, 0u);
#pragma unroll
  for (int i = 0; i < 10; ++i) {
    int e = tid + i * 448;
    if (e < 4325) {
      int f = e / 25, q = e - f * 25;
      uint2 w = make_uint2(f2bf(rg[i].x) | (f2bf(rg[i].y) << 16),
                           f2bf(rg[i].z) | (f2bf(rg[i].w) << 16));
      *reinterpret_cast<uint2*>(xs + f * 256 + ((q * 8) ^ (((f >> 1) & 15) << 3))) = w;
    }
  }
  // A1 + bias prefetch (after staging writes: keeps peak VGPR < 128)
  const uint4* __restrict__ A1p = reinterpret_cast<const uint4*>(wsb) + g * 960 + lane;
  U8 aw[15];
#pragma unroll
  for (int k = 0; k < 15; ++k) aw[k].u = A1p[k * 64];
  const int pa = c_g1p[g][0], pb = c_g1p[g][1];
  const int chbase = (h < 2) ? (pa * 8 + 4 * h) : (pb * 8 + 4 * (h - 2));
  const float4 bv0 = *reinterpret_cast<const float4*>(wsb + OFF_BF0 + chbase * 4);
  __syncthreads();

  // ---- stage1 MFMA: 15 taps x 5 nt (80 y0 rows) ----
  const uint32 offA = (c_pk1a[g] >> (8 * h)) & 255u;
  const uint32 offB = (c_pk1b[g] >> (8 * h)) & 255u;
  f32x4 acc1[5];
#pragma unroll
  for (int nt = 0; nt < 5; ++nt) acc1[nt] = (f32x4)0.f;
#pragma unroll
  for (int k = 0; k < 15; ++k) {
    const uint32 sw = (uint32)(((m16 + (k >> 1)) & 15) << 3);
    const uint32 a0 = offA ^ sw, a1o = offB ^ sw;
    const unsigned char* base = xs + (2 * m16 + k) * 256;
#pragma unroll
    for (int nt = 0; nt < 5; ++nt) {
      uint2 lo = *reinterpret_cast<const uint2*>(base + nt * 8192 + a0);
      uint2 hi = *reinterpret_cast<const uint2*>(base + nt * 8192 + a1o);
      U8 bfr; bfr.u = make_uint4(lo.x, lo.y, hi.x, hi.y);
      acc1[nt] = __builtin_amdgcn_mfma_f32_16x16x32_bf16(aw[k].s, bfr.s, acc1[nt], 0, 0, 0);
    }
  }

  // prefetch A2 ks=0 half (reuses aw regs) + stage2 bias, hidden by epilogue
  const uint4* __restrict__ A2p =
      reinterpret_cast<const uint4*>(wsb + OFF_A2) + g * 1920 + lane;
#pragma unroll
  for (int k = 0; k < 15; ++k) aw[k].u = A2p[k * 64];
  const float4 bv1 = *reinterpret_cast<const float4*>(wsb + OFF_BF1 + (g * 16 + 4 * h) * 4);

  // ---- epilogue1: bias+relu, pack bf16, masked write into ys ----
#pragma unroll
  for (int nt = 0; nt < 5; ++nt) {
    int row = nt * 16 + m16;
    int fy = f0y + row;
    float o0 = fmaxf(acc1[nt][0] + bv0.x, 0.f);
    float o1 = fmaxf(acc1[nt][1] + bv0.y, 0.f);
    float o2 = fmaxf(acc1[nt][2] + bv0.z, 0.f);
    float o3 = fmaxf(acc1[nt][3] + bv0.w, 0.f);
    uint2 wpk = make_uint2(f2bf(o0) | (f2bf(o1) << 16), f2bf(o2) | (f2bf(o3) << 16));
    if ((unsigned)fy >= 1024u) wpk = make_uint2(0u, 0u);   // y0 zero-pad
    *reinterpret_cast<uint2*>(ys + row * 256 +
        (((uint32)(chbase * 2)) ^ (((row >> 1) & 7) << 4))) = wpk;
  }
  // zero pad-node unit (bytes 224..239) of each ys row
  for (int e = tid; e < 80; e += 448)
    *reinterpret_cast<uint4*>(ys + e * 256 + (224u ^ (((e >> 1) & 7) << 4))) =
        make_uint4(0u, 0u, 0u, 0u);
  __syncthreads();

  // ---- stage2 MFMA: 2 K-steps x 15 taps x 2 nt ----
  f32x4 acc2[2];
  acc2[0] = (f32x4)0.f; acc2[1] = (f32x4)0.f;
  {
    const uint32 noff = (c_pk2[g][0] >> (8 * h)) & 255u;
#pragma unroll
    for (int k = 0; k < 15; ++k) {
      const uint32 sw = (uint32)(((m16 + (k >> 1)) & 7) << 4);
      const unsigned char* base = ys + 2 * m16 * 256 + (noff ^ sw);
      U8 b0f, b1f;
      b0f.u = *reinterpret_cast<const uint4*>(base + k * 256);
      b1f.u = *reinterpret_cast<const uint4*>(base + (k + 32) * 256);
      acc2[0] = __builtin_amdgcn_mfma_f32_16x16x32_bf16(aw[k].s, b0f.s, acc2[0], 0, 0, 0);
      acc2[1] = __builtin_amdgcn_mfma_f32_16x16x32_bf16(aw[k].s, b1f.s, acc2[1], 0, 0, 0);
    }
  }
#pragma unroll
  for (int k = 0; k < 15; ++k) aw[k].u = A2p[(15 + k) * 64];   // ks=1 half
  {
    const uint32 noff = (c_pk2[g][1] >> (8 * h)) & 255u;
#pragma unroll
    for (int k = 0; k < 15; ++k) {
      const uint32 sw = (uint32)(((m16 + (k >> 1)) & 7) << 4);
      const unsigned char* base = ys + 2 * m16 * 256 + (noff ^ sw);
      U8 b0f, b1f;
      b0f.u = *reinterpret_cast<const uint4*>(base + k * 256);
      b1f.u = *reinterpret_cast<const uint4*>(base + (k + 32) * 256);
      acc2[0] = __builtin_amdgcn_mfma_f32_16x16x32_bf16(aw[k].s, b0f.s, acc2[0], 0, 0, 0);
      acc2[1] = __builtin_amdgcn_mfma_f32_16x16x32_bf16(aw[k].s, b1f.s, acc2[1], 0, 0, 0);
    }
  }

  // ---- out store (fp32) ----
#pragma unroll
  for (int nt = 0; nt < 2; ++nt) {
    size_t obase = ((size_t)b * 112 + g * 16 + 4 * h) * 512 + t0 + nt * 16 + m16;
    out[obase]        = fmaxf(acc2[nt][0] + bv1.x, 0.f);
    out[obase + 512]  = fmaxf(acc2[nt][1] + bv1.y, 0.f);
    out[obase + 1024] = fmaxf(acc2[nt][2] + bv1.z, 0.f);
    out[obase + 1536] = fmaxf(acc2[nt][3] + bv1.w, 0.f);
  }
}

extern "C" void kernel_launch(void* const* d_in, const int* in_sizes, int n_in,
                              void* d_out, int out_size, void* d_ws, size_t ws_size,
                              hipStream_t stream) {
  const float* x  = (const float*)d_in[0];
  const float* w0 = (const float*)d_in[1];
  const float* b0 = (const float*)d_in[2];
  const float* w1 = (const float*)d_in[3];
  const float* b1 = (const float*)d_in[4];
  char* wsb = (char*)d_ws;
  float* out = (float*)d_out;

  prep_fused_weights<<<80, 256, 0, stream>>>(w0, b0, w1, b1, wsb);
  conv_fused<<<dim3(16, 64), 448, 0, stream>>>(x, wsb, out);
}